// Round 7
// baseline (324.884 us; speedup 1.0000x reference)
//
#include <hip/hip_runtime.h>
#include <hip/hip_bf16.h>

#define D 128
#define SCAN_T 256
#define SCAN_I 4
#define SCAN_CHUNK (SCAN_T * SCAN_I)

typedef __attribute__((ext_vector_type(8))) short short8;
typedef __attribute__((ext_vector_type(4))) float f32x4;
typedef __attribute__((ext_vector_type(4))) int int4v;
typedef __attribute__((ext_vector_type(4))) float float4v;
typedef __attribute__((ext_vector_type(4))) unsigned uint4v;
typedef __attribute__((ext_vector_type(2))) unsigned uint2v;
typedef _Float16 half2_t __attribute__((ext_vector_type(2)));

__device__ __forceinline__ unsigned short us_bf16(float f) {
    return __bfloat16_as_ushort(__float2bfloat16(f));
}
__device__ __forceinline__ unsigned pack_bf16(float a, float b) {
    return (unsigned)us_bf16(a) | ((unsigned)us_bf16(b) << 16);
}
__device__ __forceinline__ unsigned pack_f16(float a, float b) {
    unsigned short ua = __builtin_bit_cast(unsigned short, (_Float16)a);
    unsigned short ub = __builtin_bit_cast(unsigned short, (_Float16)b);
    return (unsigned)ua | ((unsigned)ub << 16);
}
__device__ __forceinline__ half2_t as_h2(unsigned u) {
    return __builtin_bit_cast(half2_t, u);
}
__device__ __forceinline__ half2_t shfl_h2(half2_t v, int mask) {
    return __builtin_bit_cast(half2_t,
        (unsigned)__shfl_xor(__builtin_bit_cast(int, v), mask));
}

// ---------- prep: degree histogram (nt loads) + W -> bf16 transposed ----------
__global__ __launch_bounds__(256) void k_prep(const int* __restrict__ tgt,
                                              int* __restrict__ deg, int E,
                                              const float* __restrict__ W1,
                                              const float* __restrict__ W2,
                                              unsigned short* __restrict__ W1t,
                                              unsigned short* __restrict__ W2t) {
    int i0 = blockIdx.x * blockDim.x + threadIdx.x;
    int stride = gridDim.x * blockDim.x;
    if (i0 < 16384) {
        int k = i0 >> 7, nn = i0 & 127;
        W1t[nn * 128 + k] = us_bf16(W1[i0]);
        W2t[nn * 128 + k] = us_bf16(W2[i0]);
    }
    int E4 = E >> 2;
    const int4v* tgt4 = reinterpret_cast<const int4v*>(tgt);
    for (int q = i0; q < E4; q += stride) {
        int4v t4 = __builtin_nontemporal_load(&tgt4[q]);
        atomicAdd(&deg[t4.x], 1);
        atomicAdd(&deg[t4.y], 1);
        atomicAdd(&deg[t4.z], 1);
        atomicAdd(&deg[t4.w], 1);
    }
    for (int e = E4 * 4 + i0; e < E; e += stride)
        atomicAdd(&deg[tgt[e]], 1);
}

// ---------- CSR scan ----------
__global__ __launch_bounds__(SCAN_T) void k_scan_local(const int* __restrict__ deg,
                                                       int* __restrict__ rowptr,
                                                       int* __restrict__ part, int n) {
    __shared__ int sh[SCAN_T];
    int base = blockIdx.x * SCAN_CHUNK + threadIdx.x * SCAN_I;
    int v[SCAN_I]; int tsum = 0;
    #pragma unroll
    for (int k = 0; k < SCAN_I; ++k) { int idx = base + k; v[k] = (idx < n) ? deg[idx] : 0; tsum += v[k]; }
    sh[threadIdx.x] = tsum; __syncthreads();
    for (int off = 1; off < SCAN_T; off <<= 1) {
        int o = (threadIdx.x >= (unsigned)off) ? sh[threadIdx.x - off] : 0;
        __syncthreads();
        sh[threadIdx.x] += o;
        __syncthreads();
    }
    int excl = sh[threadIdx.x] - tsum;
    #pragma unroll
    for (int k = 0; k < SCAN_I; ++k) { int idx = base + k; if (idx < n) rowptr[idx] = excl; excl += v[k]; }
    if (threadIdx.x == 0) part[blockIdx.x] = sh[SCAN_T - 1];
}

__global__ __launch_bounds__(256) void k_scan_add(int* __restrict__ rowptr,
                                                  int* __restrict__ cursor,
                                                  const int* __restrict__ part,
                                                  int nblk, int n, int E) {
    __shared__ int sp[256];
    int t = threadIdx.x;
    int v = (t < nblk) ? part[t] : 0;
    sp[t] = v; __syncthreads();
    for (int off = 1; off < 256; off <<= 1) {
        int o = (t >= off) ? sp[t - off] : 0;
        __syncthreads();
        sp[t] += o;
        __syncthreads();
    }
    int i = blockIdx.x * blockDim.x + t;
    if (i <= n) {
        int c = i / SCAN_CHUNK;
        int add = (c == 0) ? 0 : sp[c - 1];
        if (i < n) { int r = rowptr[i] + add; rowptr[i] = r; cursor[i] = r; }
        else rowptr[n] = E;
    }
}

// ---------- XCD-sliced reorder + fused x->f16 conversion ----------
// All streaming traffic is non-temporal so each slice's csr window (~1.6 MB)
// survives in its XCD L2 long enough for sibling 8B stores to merge into
// full lines -> single clean writeback. csr.y stores exp(w) (max-free is
// numerically safe for w~N(0,1); removes all exps from k_agg).
__global__ __launch_bounds__(256) void k_reorder(const int* __restrict__ src,
                                                 const int* __restrict__ tgt,
                                                 const float* __restrict__ ew,
                                                 int* __restrict__ cursor,
                                                 int2* __restrict__ csr, int E, int sliceN,
                                                 const float* __restrict__ x,
                                                 unsigned* __restrict__ xh, int nf4) {
    int tidAll = blockIdx.x * blockDim.x + threadIdx.x;
    int strideAll = gridDim.x * blockDim.x;

    auto conv = [&]() {
        const float4v* x4 = reinterpret_cast<const float4v*>(x);
        uint2v* xh2 = reinterpret_cast<uint2v*>(xh);
        for (int i = tidAll; i < nf4; i += strideAll) {
            float4v v = __builtin_nontemporal_load(&x4[i]);
            uint2v o;
            o.x = pack_f16(v.x, v.y);
            o.y = pack_f16(v.z, v.w);
            __builtin_nontemporal_store(o, &xh2[i]);
        }
    };

    bool convFirst = (blockIdx.x & 8) != 0;
    if (convFirst) conv();

    int slice = blockIdx.x & 7;
    int lo = slice * sliceN, hi = lo + sliceN;
    int tpslice = (gridDim.x >> 3) * blockDim.x;
    int i = (blockIdx.x >> 3) * blockDim.x + threadIdx.x;
    int E4 = E >> 2;
    const int4v* tgt4 = reinterpret_cast<const int4v*>(tgt);
    for (int q = i; q < E4; q += tpslice) {
        int4v t4 = __builtin_nontemporal_load(&tgt4[q]);
        int e0 = q * 4;
        #pragma unroll
        for (int k = 0; k < 4; ++k) {
            int t = (k == 0) ? t4.x : (k == 1) ? t4.y : (k == 2) ? t4.z : t4.w;
            if (t >= lo && t < hi) {
                int e = e0 + k;
                int pos = atomicAdd(&cursor[t], 1);
                int   sv = __builtin_nontemporal_load(&src[e]);
                float wv = __builtin_nontemporal_load(&ew[e]);
                csr[pos] = make_int2(sv, __float_as_int(__expf(wv)));
            }
        }
    }
    for (int e = E4 * 4 + i; e < E; e += tpslice) {
        int t = tgt[e];
        if (t >= lo && t < hi) {
            int pos = atomicAdd(&cursor[t], 1);
            csr[pos] = make_int2(src[e], __float_as_int(__expf(ew[e])));
        }
    }

    if (!convFirst) conv();
}

// ---------- aggregate: 1 wave per node; no exp, no shuffles in hot loop ----------
// lane = eg*16+dg. Edge-group eg handles edge base+i*4+eg (4 edges in flight/wave);
// each 16-lane group broadcast-reads its int2 (4 consecutive entries = 32B/wave),
// dim-group dg loads a uint4 (8 f16 dims) of the source row; 4 pk_fma per edge.
__global__ __launch_bounds__(256) void k_agg(
    const int* __restrict__ rowptr, const int2* __restrict__ csr,
    const uint4v* __restrict__ xh4, uint4v* __restrict__ cmb4, int n)
{
    int w = threadIdx.x >> 6;
    int lane = threadIdx.x & 63;
    int node = blockIdx.x * 4 + w;
    if (node >= n) node = n - 1;   // benign duplicate on tail

    int r0 = rowptr[node], r1 = rowptr[node + 1];
    int cnt = r1 - r0;

    // denominator: plain sum of precomputed exp(w)
    float s = 0.f;
    for (int c = r0 + lane; c < r1; c += 64) s += __int_as_float(csr[c].y);
    #pragma unroll
    for (int off = 32; off; off >>= 1) s += __shfl_xor(s, off);
    float inv = (s > 0.f) ? (1.f / s) : 0.f;

    int eg = lane >> 4;
    int dg = lane & 15;

    half2_t h0 = (half2_t)0, h1 = (half2_t)0, h2 = (half2_t)0, h3 = (half2_t)0;

    int last = (cnt > 0) ? cnt - 1 : 0;
    for (int base = 0; base < cnt; base += 16) {
        #pragma unroll
        for (int i = 0; i < 4; ++i) {
            if (base + i * 4 >= cnt) break;    // wave-uniform
            int e = base + i * 4 + eg;
            int2 cr = csr[r0 + (e < cnt ? e : last)];
            float wn = (e < cnt) ? __int_as_float(cr.y) * inv : 0.f;
            _Float16 wh = (_Float16)wn;
            half2_t w2 = {wh, wh};
            uint4v v = xh4[cr.x * 16 + dg];
            h0 += w2 * as_h2(v.x);
            h1 += w2 * as_h2(v.y);
            h2 += w2 * as_h2(v.z);
            h3 += w2 * as_h2(v.w);
        }
    }

    // reduce across the 4 edge-groups
    h0 += shfl_h2(h0, 16); h0 += shfl_h2(h0, 32);
    h1 += shfl_h2(h1, 16); h1 += shfl_h2(h1, 32);
    h2 += shfl_h2(h2, 16); h2 += shfl_h2(h2, 32);
    h3 += shfl_h2(h3, 16); h3 += shfl_h2(h3, 32);

    float a0 = (float)h0.x, a1 = (float)h0.y, a2 = (float)h1.x, a3 = (float)h1.y;
    float a4 = (float)h2.x, a5 = (float)h2.y, a6 = (float)h3.x, a7 = (float)h3.y;

    float ss = a0 * a0;
    ss = fmaf(a1, a1, ss); ss = fmaf(a2, a2, ss); ss = fmaf(a3, a3, ss);
    ss = fmaf(a4, a4, ss); ss = fmaf(a5, a5, ss); ss = fmaf(a6, a6, ss);
    ss = fmaf(a7, a7, ss);
    #pragma unroll
    for (int off = 8; off; off >>= 1) ss += __shfl_xor(ss, off);
    float rn = 1.f / (sqrtf(ss) + 1e-9f);

    if (eg == 0) {
        uint4v hx = xh4[node * 16 + dg];
        half2_t x0 = as_h2(hx.x), x1 = as_h2(hx.y), x2 = as_h2(hx.z), x3 = as_h2(hx.w);
        uint4v o;
        o.x = pack_bf16((float)x0.x + a0 * rn, (float)x0.y + a1 * rn);
        o.y = pack_bf16((float)x1.x + a2 * rn, (float)x1.y + a3 * rn);
        o.z = pack_bf16((float)x2.x + a4 * rn, (float)x2.y + a5 * rn);
        o.w = pack_bf16((float)x3.x + a6 * rn, (float)x3.y + a7 * rn);
        cmb4[node * 16 + dg] = o;
    }
}

// ---------- MLP + LN via MFMA: 64 nodes/block; W read from global (L1/L2) ----------
__global__ __launch_bounds__(256) void k_mlp(
    const uint4v* __restrict__ cmb4,
    const unsigned short* __restrict__ W1t, const unsigned short* __restrict__ W2t,
    const float* __restrict__ b1, const float* __restrict__ b2,
    const float* __restrict__ gamma, const float* __restrict__ beta,
    float* __restrict__ out, int n)
{
    __shared__ __align__(16) unsigned short sA[64][136];

    int node0 = blockIdx.x * 64;
    int w = threadIdx.x >> 6;
    int lane = threadIdx.x & 63;
    int lr = lane & 15;
    int lg = lane >> 4;
    int mr = w * 16;

    for (int idx = threadIdx.x; idx < 64 * 16; idx += 256) {
        int row = idx >> 4, seg = idx & 15;
        int gr = node0 + row; if (gr >= n) gr = n - 1;
        uint4v v = cmb4[gr * 16 + seg];
        *reinterpret_cast<uint4v*>(&sA[row][seg * 8]) = v;
    }
    __syncthreads();

    short8 aF[4];
    #pragma unroll
    for (int kt = 0; kt < 4; ++kt)
        aF[kt] = *reinterpret_cast<const short8*>(&sA[mr + lr][kt * 32 + lg * 8]);

    #pragma unroll
    for (int nt = 0; nt < 8; ++nt) {
        f32x4 c = {0.f, 0.f, 0.f, 0.f};
        #pragma unroll
        for (int kt = 0; kt < 4; ++kt) {
            short8 bF = *reinterpret_cast<const short8*>(
                &W1t[(nt * 16 + lr) * 128 + kt * 32 + lg * 8]);
            c = __builtin_amdgcn_mfma_f32_16x16x32_bf16(aF[kt], bF, c, 0, 0, 0);
        }
        float b1v = b1[nt * 16 + lr];
        #pragma unroll
        for (int reg = 0; reg < 4; ++reg) {
            float h = fmaxf(c[reg] + b1v, 0.f);
            sA[mr + lg * 4 + reg][nt * 16 + lr] = us_bf16(h);   // wave-local rows
        }
    }
    __syncthreads();   // cheap; guarantees h writes visible for fragment reload

    short8 a2F[4];
    #pragma unroll
    for (int kt = 0; kt < 4; ++kt)
        a2F[kt] = *reinterpret_cast<const short8*>(&sA[mr + lr][kt * 32 + lg * 8]);

    f32x4 c2[8];
    float b2v[8], gv[8], bev[8];
    #pragma unroll
    for (int nt = 0; nt < 8; ++nt) {
        c2[nt] = (f32x4){0.f, 0.f, 0.f, 0.f};
        #pragma unroll
        for (int kt = 0; kt < 4; ++kt) {
            short8 bF = *reinterpret_cast<const short8*>(
                &W2t[(nt * 16 + lr) * 128 + kt * 32 + lg * 8]);
            c2[nt] = __builtin_amdgcn_mfma_f32_16x16x32_bf16(a2F[kt], bF, c2[nt], 0, 0, 0);
        }
        int col = nt * 16 + lr;
        b2v[nt] = b2[col]; gv[nt] = gamma[col]; bev[nt] = beta[col];
    }

    float rs[4] = {0.f, 0.f, 0.f, 0.f}, sq[4] = {0.f, 0.f, 0.f, 0.f};
    #pragma unroll
    for (int nt = 0; nt < 8; ++nt)
        #pragma unroll
        for (int reg = 0; reg < 4; ++reg) {
            float v = c2[nt][reg] + b2v[nt];
            rs[reg] += v; sq[reg] += v * v;
        }
    #pragma unroll
    for (int off = 1; off <= 8; off <<= 1)
        #pragma unroll
        for (int reg = 0; reg < 4; ++reg) {
            rs[reg] += __shfl_xor(rs[reg], off);
            sq[reg] += __shfl_xor(sq[reg], off);
        }
    float mu[4], rstd[4];
    #pragma unroll
    for (int reg = 0; reg < 4; ++reg) {
        mu[reg] = rs[reg] * (1.f / 128.f);
        float var = sq[reg] * (1.f / 128.f) - mu[reg] * mu[reg];
        rstd[reg] = rsqrtf(var + 1e-5f);
    }

    #pragma unroll
    for (int nt = 0; nt < 8; ++nt)
        #pragma unroll
        for (int reg = 0; reg < 4; ++reg) {
            int gr = node0 + mr + lg * 4 + reg;
            if (gr < n) {
                float v = c2[nt][reg] + b2v[nt];
                out[gr * 128 + nt * 16 + lr] = gv[nt] * (v - mu[reg]) * rstd[reg] + bev[nt];
            }
        }
}

extern "C" void kernel_launch(void* const* d_in, const int* in_sizes, int n_in,
                              void* d_out, int out_size, void* d_ws, size_t ws_size,
                              hipStream_t stream) {
    const float* x     = (const float*)d_in[0];
    const int*   ei    = (const int*)d_in[1];
    const float* ew    = (const float*)d_in[2];
    const float* W1    = (const float*)d_in[3];
    const float* b1    = (const float*)d_in[4];
    const float* W2    = (const float*)d_in[5];
    const float* b2    = (const float*)d_in[6];
    const float* gamma = (const float*)d_in[7];
    const float* beta  = (const float*)d_in[8];

    int n = in_sizes[0] / D;
    int E = in_sizes[2];
    const int* src = ei;
    const int* tgt = ei + E;

    char* ws = (char*)d_ws;
    int2*     csr    = (int2*)ws;     ws += (size_t)E * sizeof(int2);
    unsigned* xh     = (unsigned*)ws; ws += (size_t)n * 64 * sizeof(unsigned);
    unsigned* cmb    = (unsigned*)ws; ws += (size_t)n * 64 * sizeof(unsigned);
    unsigned short* W1t = (unsigned short*)ws; ws += 128 * 128 * sizeof(unsigned short);
    unsigned short* W2t = (unsigned short*)ws; ws += 128 * 128 * sizeof(unsigned short);
    int*      deg    = (int*)ws;      ws += (size_t)n * sizeof(int);
    int*      rowptr = (int*)ws;      ws += ((size_t)n + 1) * sizeof(int);
    int*      cursor = (int*)ws;      ws += (size_t)n * sizeof(int);
    int*      part   = (int*)ws;      ws += (size_t)SCAN_T * sizeof(int);

    hipMemsetAsync((void*)deg, 0, (size_t)n * sizeof(int), stream);

    k_prep<<<2048, 256, 0, stream>>>(tgt, deg, E, W1, W2, W1t, W2t);

    int nblk = (n + SCAN_CHUNK - 1) / SCAN_CHUNK;   // 98 (<=256)
    k_scan_local<<<nblk, SCAN_T, 0, stream>>>(deg, rowptr, part, n);
    k_scan_add<<<(n + 256) / 256, 256, 0, stream>>>(rowptr, cursor, part, nblk, n, E);

    int sliceN = (n + 7) / 8;
    int nf4 = n * D / 4;
    k_reorder<<<2048, 256, 0, stream>>>(src, tgt, ew, cursor, csr, E, sliceN,
                                        x, xh, nf4);

    k_agg<<<(n + 3) / 4, 256, 0, stream>>>(rowptr, csr,
                                           (const uint4v*)xh, (uint4v*)cmb, n);

    k_mlp<<<(n + 63) / 64, 256, 0, stream>>>((const uint4v*)cmb, W1t, W2t,
                                             b1, b2, gamma, beta,
                                             (float*)d_out, n);
}

// Round 8
// 283.291 us; speedup vs baseline: 1.1468x; 1.1468x over previous
//
#include <hip/hip_runtime.h>
#include <hip/hip_bf16.h>

#define D 128
#define SCAN_T 256
#define SCAN_I 4
#define SCAN_CHUNK (SCAN_T * SCAN_I)
#define CH 2048          // edges per k_binA block
#define BSH 9            // log2(nodes per bucket) -> 512; valid for n <= 131072

typedef __attribute__((ext_vector_type(8))) short short8;
typedef __attribute__((ext_vector_type(4))) float f32x4;
typedef __attribute__((ext_vector_type(4))) int int4v;
typedef __attribute__((ext_vector_type(4))) float float4v;
typedef __attribute__((ext_vector_type(4))) unsigned uint4v;
typedef __attribute__((ext_vector_type(2))) unsigned uint2v;
typedef _Float16 half2_t __attribute__((ext_vector_type(2)));

__device__ __forceinline__ unsigned short us_bf16(float f) {
    return __bfloat16_as_ushort(__float2bfloat16(f));
}
__device__ __forceinline__ unsigned pack_bf16(float a, float b) {
    return (unsigned)us_bf16(a) | ((unsigned)us_bf16(b) << 16);
}
__device__ __forceinline__ unsigned pack_f16(float a, float b) {
    unsigned short ua = __builtin_bit_cast(unsigned short, (_Float16)a);
    unsigned short ub = __builtin_bit_cast(unsigned short, (_Float16)b);
    return (unsigned)ua | ((unsigned)ub << 16);
}
__device__ __forceinline__ half2_t as_h2(unsigned u) {
    return __builtin_bit_cast(half2_t, u);
}
__device__ __forceinline__ half2_t shfl_h2(half2_t v, int mask) {
    return __builtin_bit_cast(half2_t,
        (unsigned)__shfl_xor(__builtin_bit_cast(int, v), mask));
}

// ---------- prep: x->f16, W->bf16 transposed, degree histogram ----------
__global__ __launch_bounds__(256) void k_prep(const float* __restrict__ x,
                                              unsigned* __restrict__ xh, int nf4,
                                              const float* __restrict__ W1,
                                              const float* __restrict__ W2,
                                              unsigned short* __restrict__ W1t,
                                              unsigned short* __restrict__ W2t,
                                              const int* __restrict__ tgt,
                                              int* __restrict__ deg, int E) {
    int i0 = blockIdx.x * blockDim.x + threadIdx.x;
    int stride = gridDim.x * blockDim.x;
    const float4v* x4 = reinterpret_cast<const float4v*>(x);
    uint2v* xh2 = reinterpret_cast<uint2v*>(xh);
    for (int i = i0; i < nf4; i += stride) {
        float4v v = __builtin_nontemporal_load(&x4[i]);
        uint2v o;
        o.x = pack_f16(v.x, v.y);
        o.y = pack_f16(v.z, v.w);
        __builtin_nontemporal_store(o, &xh2[i]);
    }
    if (i0 < 16384) {
        int k = i0 >> 7, nn = i0 & 127;
        W1t[nn * 128 + k] = us_bf16(W1[i0]);
        W2t[nn * 128 + k] = us_bf16(W2[i0]);
    }
    int E4 = E >> 2;
    const int4v* tgt4 = reinterpret_cast<const int4v*>(tgt);
    for (int q = i0; q < E4; q += stride) {
        int4v t4 = __builtin_nontemporal_load(&tgt4[q]);
        atomicAdd(&deg[t4.x], 1);
        atomicAdd(&deg[t4.y], 1);
        atomicAdd(&deg[t4.z], 1);
        atomicAdd(&deg[t4.w], 1);
    }
    for (int e = E4 * 4 + i0; e < E; e += stride)
        atomicAdd(&deg[tgt[e]], 1);
}

// ---------- CSR scan ----------
__global__ __launch_bounds__(SCAN_T) void k_scan_local(const int* __restrict__ deg,
                                                       int* __restrict__ rowptr,
                                                       int* __restrict__ part, int n) {
    __shared__ int sh[SCAN_T];
    int base = blockIdx.x * SCAN_CHUNK + threadIdx.x * SCAN_I;
    int v[SCAN_I]; int tsum = 0;
    #pragma unroll
    for (int k = 0; k < SCAN_I; ++k) { int idx = base + k; v[k] = (idx < n) ? deg[idx] : 0; tsum += v[k]; }
    sh[threadIdx.x] = tsum; __syncthreads();
    for (int off = 1; off < SCAN_T; off <<= 1) {
        int o = (threadIdx.x >= (unsigned)off) ? sh[threadIdx.x - off] : 0;
        __syncthreads();
        sh[threadIdx.x] += o;
        __syncthreads();
    }
    int excl = sh[threadIdx.x] - tsum;
    #pragma unroll
    for (int k = 0; k < SCAN_I; ++k) { int idx = base + k; if (idx < n) rowptr[idx] = excl; excl += v[k]; }
    if (threadIdx.x == 0) part[blockIdx.x] = sh[SCAN_T - 1];
}

// finalizes rowptr and seeds per-bucket append cursors (bcur[b] = rowptr[b<<BSH])
__global__ __launch_bounds__(256) void k_scan_add(int* __restrict__ rowptr,
                                                  int* __restrict__ bcur,
                                                  const int* __restrict__ part,
                                                  int nblk, int n, int E) {
    __shared__ int sp[256];
    int t = threadIdx.x;
    int v = (t < nblk) ? part[t] : 0;
    sp[t] = v; __syncthreads();
    for (int off = 1; off < 256; off <<= 1) {
        int o = (t >= off) ? sp[t - off] : 0;
        __syncthreads();
        sp[t] += o;
        __syncthreads();
    }
    int i = blockIdx.x * blockDim.x + t;
    if (i <= n) {
        int c = i / SCAN_CHUNK;
        int add = (c == 0) ? 0 : sp[c - 1];
        if (i < n) {
            int r = rowptr[i] + add;
            rowptr[i] = r;
            if ((i & ((1 << BSH) - 1)) == 0) bcur[i >> BSH] = r;
        } else rowptr[n] = E;
    }
}

// ---------- pass A: LDS-binned bucket append ----------
// Each block bins CH edges into buckets of 512 target-nodes inside LDS, then
// flushes contiguous per-bucket runs (one cursor atomic per bucket) -> all
// global writes are line-dense. Record: (src, tgtLocal<<16 | f16bits(exp(w))).
__global__ __launch_bounds__(256) void k_binA(
    const int* __restrict__ src, const int* __restrict__ tgt,
    const float* __restrict__ ew, int* __restrict__ bcur,
    int2* __restrict__ stage, int E, int nbuk)
{
    __shared__ int2 recs[CH];
    __shared__ unsigned short bslot[CH];
    __shared__ int sh[256];
    __shared__ int lbase[256];
    __shared__ int gofs[256];

    int tid = threadIdx.x;
    int c0 = blockIdx.x * CH;
    int chunkCnt = min(CH, E - c0);

    sh[tid] = 0;
    __syncthreads();

    int myb[8], mypos[8], mysrc[8]; unsigned myy[8];
    #pragma unroll
    for (int k = 0; k < 8; ++k) {
        int idx = k * 256 + tid;
        myb[k] = -1;
        if (idx < chunkCnt) {
            int e = c0 + idx;
            int t = tgt[e];
            int b = t >> BSH;
            float expw = __expf(ew[e]);
            unsigned short h = __builtin_bit_cast(unsigned short, (_Float16)expw);
            myb[k] = b;
            myy[k] = ((unsigned)(t & ((1 << BSH) - 1)) << 16) | (unsigned)h;
            mysrc[k] = src[e];
            mypos[k] = atomicAdd(&sh[b], 1);
        }
    }
    __syncthreads();
    int cnt_b = sh[tid];
    for (int off = 1; off < 256; off <<= 1) {
        int o = (tid >= off) ? sh[tid - off] : 0;
        __syncthreads();
        sh[tid] += o;
        __syncthreads();
    }
    int lb = sh[tid] - cnt_b;
    lbase[tid] = lb;
    if (cnt_b > 0 && tid < nbuk) {
        int gb = atomicAdd(&bcur[tid], cnt_b);
        gofs[tid] = gb - lb;
    }
    __syncthreads();
    #pragma unroll
    for (int k = 0; k < 8; ++k) {
        if (myb[k] >= 0) {
            int slot = lbase[myb[k]] + mypos[k];
            recs[slot] = make_int2(mysrc[k], (int)myy[k]);
            bslot[slot] = (unsigned short)myb[k];
        }
    }
    __syncthreads();
    for (int i = tid; i < chunkCnt; i += 256) {
        int b = bslot[i];
        stage[gofs[b] + i] = recs[i];
    }
}

// ---------- pass B: per-bucket scatter to final CSR + softmax normalize ----------
// One block owns one bucket: its csr window (~64KB) is written only by this
// block -> full-line writebacks. Denominators accumulate in LDS f32; csr.y
// stores the normalized weight duplicated as half2 for k_agg.
__global__ __launch_bounds__(256) void k_binB(
    const int* __restrict__ rowptr, const int2* __restrict__ stage,
    int2* __restrict__ csr, int n)
{
    __shared__ int lcur[1 << BSH];
    __shared__ float ldenom[1 << BSH];
    int b = blockIdx.x;
    int tid = threadIdx.x;
    int node0 = b << BSH;
    int nn = min(1 << BSH, n - node0);
    for (int j = tid; j < nn; j += 256) {
        lcur[j] = rowptr[node0 + j];
        ldenom[j] = 0.f;
    }
    __syncthreads();
    int s0 = rowptr[node0];
    int s1 = rowptr[min(node0 + (1 << BSH), n)];
    for (int i = s0 + tid; i < s1; i += 256) {
        int2 rec = stage[i];
        int tl = ((unsigned)rec.y) >> 16;
        _Float16 hw = __builtin_bit_cast(_Float16, (unsigned short)(rec.y & 0xffff));
        atomicAdd(&ldenom[tl], (float)hw);
    }
    __syncthreads();
    for (int j = tid; j < nn; j += 256) {
        float d = ldenom[j];
        ldenom[j] = (d > 0.f) ? (1.f / d) : 0.f;
    }
    __syncthreads();
    for (int i = s0 + tid; i < s1; i += 256) {
        int2 rec = stage[i];
        int tl = ((unsigned)rec.y) >> 16;
        _Float16 hw = __builtin_bit_cast(_Float16, (unsigned short)(rec.y & 0xffff));
        float wn = (float)hw * ldenom[tl];
        unsigned short wb = __builtin_bit_cast(unsigned short, (_Float16)wn);
        unsigned wp = (unsigned)wb | ((unsigned)wb << 16);
        int pos = atomicAdd(&lcur[tl], 1);
        csr[pos] = make_int2(rec.x, (int)wp);
    }
}

// ---------- aggregate: 1 wave per node; pure gather (weights pre-normalized) ----------
__global__ __launch_bounds__(256) void k_agg(
    const int* __restrict__ rowptr, const int2* __restrict__ csr,
    const uint4v* __restrict__ xh4, uint4v* __restrict__ cmb4, int n)
{
    int w = threadIdx.x >> 6;
    int lane = threadIdx.x & 63;
    int node = blockIdx.x * 4 + w;
    if (node >= n) node = n - 1;   // benign duplicate on tail

    int r0 = rowptr[node], r1 = rowptr[node + 1];
    int cnt = r1 - r0;

    int eg = lane >> 4;
    int dg = lane & 15;

    half2_t h0 = (half2_t)0, h1 = (half2_t)0, h2 = (half2_t)0, h3 = (half2_t)0;

    int last = (cnt > 0) ? cnt - 1 : 0;
    for (int base = 0; base < cnt; base += 16) {
        #pragma unroll
        for (int i = 0; i < 4; ++i) {
            if (base + i * 4 >= cnt) break;    // wave-uniform
            int e = base + i * 4 + eg;
            bool valid = e < cnt;
            int2 cr = csr[r0 + (valid ? e : last)];
            half2_t w2 = as_h2(valid ? (unsigned)cr.y : 0u);
            uint4v v = xh4[cr.x * 16 + dg];
            h0 += w2 * as_h2(v.x);
            h1 += w2 * as_h2(v.y);
            h2 += w2 * as_h2(v.z);
            h3 += w2 * as_h2(v.w);
        }
    }

    h0 += shfl_h2(h0, 16); h0 += shfl_h2(h0, 32);
    h1 += shfl_h2(h1, 16); h1 += shfl_h2(h1, 32);
    h2 += shfl_h2(h2, 16); h2 += shfl_h2(h2, 32);
    h3 += shfl_h2(h3, 16); h3 += shfl_h2(h3, 32);

    float a0 = (float)h0.x, a1 = (float)h0.y, a2 = (float)h1.x, a3 = (float)h1.y;
    float a4 = (float)h2.x, a5 = (float)h2.y, a6 = (float)h3.x, a7 = (float)h3.y;

    float ss = a0 * a0;
    ss = fmaf(a1, a1, ss); ss = fmaf(a2, a2, ss); ss = fmaf(a3, a3, ss);
    ss = fmaf(a4, a4, ss); ss = fmaf(a5, a5, ss); ss = fmaf(a6, a6, ss);
    ss = fmaf(a7, a7, ss);
    #pragma unroll
    for (int off = 8; off; off >>= 1) ss += __shfl_xor(ss, off);
    float rn = 1.f / (sqrtf(ss) + 1e-9f);

    if (eg == 0) {
        uint4v hx = xh4[node * 16 + dg];
        half2_t x0 = as_h2(hx.x), x1 = as_h2(hx.y), x2 = as_h2(hx.z), x3 = as_h2(hx.w);
        uint4v o;
        o.x = pack_bf16((float)x0.x + a0 * rn, (float)x0.y + a1 * rn);
        o.y = pack_bf16((float)x1.x + a2 * rn, (float)x1.y + a3 * rn);
        o.z = pack_bf16((float)x2.x + a4 * rn, (float)x2.y + a5 * rn);
        o.w = pack_bf16((float)x3.x + a6 * rn, (float)x3.y + a7 * rn);
        cmb4[node * 16 + dg] = o;
    }
}

// ---------- MLP + LN via MFMA: 64 nodes/block; W read from global (L1/L2) ----------
__global__ __launch_bounds__(256) void k_mlp(
    const uint4v* __restrict__ cmb4,
    const unsigned short* __restrict__ W1t, const unsigned short* __restrict__ W2t,
    const float* __restrict__ b1, const float* __restrict__ b2,
    const float* __restrict__ gamma, const float* __restrict__ beta,
    float* __restrict__ out, int n)
{
    __shared__ __align__(16) unsigned short sA[64][136];

    int node0 = blockIdx.x * 64;
    int w = threadIdx.x >> 6;
    int lane = threadIdx.x & 63;
    int lr = lane & 15;
    int lg = lane >> 4;
    int mr = w * 16;

    for (int idx = threadIdx.x; idx < 64 * 16; idx += 256) {
        int row = idx >> 4, seg = idx & 15;
        int gr = node0 + row; if (gr >= n) gr = n - 1;
        uint4v v = cmb4[gr * 16 + seg];
        *reinterpret_cast<uint4v*>(&sA[row][seg * 8]) = v;
    }
    __syncthreads();

    short8 aF[4];
    #pragma unroll
    for (int kt = 0; kt < 4; ++kt)
        aF[kt] = *reinterpret_cast<const short8*>(&sA[mr + lr][kt * 32 + lg * 8]);

    #pragma unroll
    for (int nt = 0; nt < 8; ++nt) {
        f32x4 c = {0.f, 0.f, 0.f, 0.f};
        #pragma unroll
        for (int kt = 0; kt < 4; ++kt) {
            short8 bF = *reinterpret_cast<const short8*>(
                &W1t[(nt * 16 + lr) * 128 + kt * 32 + lg * 8]);
            c = __builtin_amdgcn_mfma_f32_16x16x32_bf16(aF[kt], bF, c, 0, 0, 0);
        }
        float b1v = b1[nt * 16 + lr];
        #pragma unroll
        for (int reg = 0; reg < 4; ++reg) {
            float h = fmaxf(c[reg] + b1v, 0.f);
            sA[mr + lg * 4 + reg][nt * 16 + lr] = us_bf16(h);
        }
    }
    __syncthreads();

    short8 a2F[4];
    #pragma unroll
    for (int kt = 0; kt < 4; ++kt)
        a2F[kt] = *reinterpret_cast<const short8*>(&sA[mr + lr][kt * 32 + lg * 8]);

    f32x4 c2[8];
    float b2v[8], gv[8], bev[8];
    #pragma unroll
    for (int nt = 0; nt < 8; ++nt) {
        c2[nt] = (f32x4){0.f, 0.f, 0.f, 0.f};
        #pragma unroll
        for (int kt = 0; kt < 4; ++kt) {
            short8 bF = *reinterpret_cast<const short8*>(
                &W2t[(nt * 16 + lr) * 128 + kt * 32 + lg * 8]);
            c2[nt] = __builtin_amdgcn_mfma_f32_16x16x32_bf16(a2F[kt], bF, c2[nt], 0, 0, 0);
        }
        int col = nt * 16 + lr;
        b2v[nt] = b2[col]; gv[nt] = gamma[col]; bev[nt] = beta[col];
    }

    float rs[4] = {0.f, 0.f, 0.f, 0.f}, sq[4] = {0.f, 0.f, 0.f, 0.f};
    #pragma unroll
    for (int nt = 0; nt < 8; ++nt)
        #pragma unroll
        for (int reg = 0; reg < 4; ++reg) {
            float v = c2[nt][reg] + b2v[nt];
            rs[reg] += v; sq[reg] += v * v;
        }
    #pragma unroll
    for (int off = 1; off <= 8; off <<= 1)
        #pragma unroll
        for (int reg = 0; reg < 4; ++reg) {
            rs[reg] += __shfl_xor(rs[reg], off);
            sq[reg] += __shfl_xor(sq[reg], off);
        }
    float mu[4], rstd[4];
    #pragma unroll
    for (int reg = 0; reg < 4; ++reg) {
        mu[reg] = rs[reg] * (1.f / 128.f);
        float var = sq[reg] * (1.f / 128.f) - mu[reg] * mu[reg];
        rstd[reg] = rsqrtf(var + 1e-5f);
    }

    #pragma unroll
    for (int nt = 0; nt < 8; ++nt)
        #pragma unroll
        for (int reg = 0; reg < 4; ++reg) {
            int gr = node0 + mr + lg * 4 + reg;
            if (gr < n) {
                float v = c2[nt][reg] + b2v[nt];
                out[gr * 128 + nt * 16 + lr] = gv[nt] * (v - mu[reg]) * rstd[reg] + bev[nt];
            }
        }
}

extern "C" void kernel_launch(void* const* d_in, const int* in_sizes, int n_in,
                              void* d_out, int out_size, void* d_ws, size_t ws_size,
                              hipStream_t stream) {
    const float* x     = (const float*)d_in[0];
    const int*   ei    = (const int*)d_in[1];
    const float* ew    = (const float*)d_in[2];
    const float* W1    = (const float*)d_in[3];
    const float* b1    = (const float*)d_in[4];
    const float* W2    = (const float*)d_in[5];
    const float* b2    = (const float*)d_in[6];
    const float* gamma = (const float*)d_in[7];
    const float* beta  = (const float*)d_in[8];

    int n = in_sizes[0] / D;
    int E = in_sizes[2];
    const int* src = ei;
    const int* tgt = ei + E;

    char* ws = (char*)d_ws;
    int2*     csr    = (int2*)ws;     ws += (size_t)E * sizeof(int2);
    unsigned* xh     = (unsigned*)ws; ws += (size_t)n * 64 * sizeof(unsigned);
    unsigned* cmb    = (unsigned*)ws; ws += (size_t)n * 64 * sizeof(unsigned);
    unsigned short* W1t = (unsigned short*)ws; ws += 128 * 128 * sizeof(unsigned short);
    unsigned short* W2t = (unsigned short*)ws; ws += 128 * 128 * sizeof(unsigned short);
    int*      deg    = (int*)ws;      ws += (size_t)n * sizeof(int);
    int*      rowptr = (int*)ws;      ws += ((size_t)n + 1) * sizeof(int);
    int*      bcur   = (int*)ws;      ws += 256 * sizeof(int);
    int*      part   = (int*)ws;      ws += (size_t)SCAN_T * sizeof(int);
    // stage aliases cmb: stage is consumed by k_binB before k_agg writes cmb
    int2*     stage  = (int2*)cmb;

    hipMemsetAsync((void*)deg, 0, (size_t)n * sizeof(int), stream);

    int nf4 = n * D / 4;
    k_prep<<<2048, 256, 0, stream>>>(x, xh, nf4, W1, W2, W1t, W2t, tgt, deg, E);

    int nblk = (n + SCAN_CHUNK - 1) / SCAN_CHUNK;   // 98 (<=256)
    k_scan_local<<<nblk, SCAN_T, 0, stream>>>(deg, rowptr, part, n);
    k_scan_add<<<(n + 256) / 256, 256, 0, stream>>>(rowptr, bcur, part, nblk, n, E);

    int nbuk = (n + (1 << BSH) - 1) >> BSH;         // 196 for n=100000
    int nchunk = (E + CH - 1) / CH;                 // 782
    k_binA<<<nchunk, 256, 0, stream>>>(src, tgt, ew, bcur, stage, E, nbuk);
    k_binB<<<nbuk, 256, 0, stream>>>(rowptr, stage, csr, n);

    k_agg<<<(n + 3) / 4, 256, 0, stream>>>(rowptr, csr,
                                           (const uint4v*)xh, (uint4v*)cmb, n);

    k_mlp<<<(n + 63) / 64, 256, 0, stream>>>((const uint4v*)cmb, W1t, W2t,
                                             b1, b2, gamma, beta,
                                             (float*)d_out, n);
}

// Round 9
// 279.606 us; speedup vs baseline: 1.1619x; 1.0132x over previous
//
#include <hip/hip_runtime.h>
#include <hip/hip_bf16.h>

#define D 128
#define SCAN_T 256
#define SCAN_I 4
#define SCAN_CHUNK (SCAN_T * SCAN_I)
#define CH 2048          // edges per k_binA block
#define BSH 9            // log2(nodes per bucket) -> 512; valid for n <= 131072

typedef __attribute__((ext_vector_type(8))) short short8;
typedef __attribute__((ext_vector_type(4))) float f32x4;
typedef __attribute__((ext_vector_type(4))) int int4v;
typedef __attribute__((ext_vector_type(4))) float float4v;
typedef __attribute__((ext_vector_type(4))) unsigned uint4v;
typedef __attribute__((ext_vector_type(2))) unsigned uint2v;
typedef _Float16 half2_t __attribute__((ext_vector_type(2)));

__device__ __forceinline__ unsigned short us_bf16(float f) {
    return __bfloat16_as_ushort(__float2bfloat16(f));
}
__device__ __forceinline__ unsigned pack_bf16(float a, float b) {
    return (unsigned)us_bf16(a) | ((unsigned)us_bf16(b) << 16);
}
__device__ __forceinline__ unsigned pack_f16(float a, float b) {
    unsigned short ua = __builtin_bit_cast(unsigned short, (_Float16)a);
    unsigned short ub = __builtin_bit_cast(unsigned short, (_Float16)b);
    return (unsigned)ua | ((unsigned)ub << 16);
}
__device__ __forceinline__ half2_t as_h2(unsigned u) {
    return __builtin_bit_cast(half2_t, u);
}
__device__ __forceinline__ half2_t shfl_h2(half2_t v, int mask) {
    return __builtin_bit_cast(half2_t,
        (unsigned)__shfl_xor(__builtin_bit_cast(int, v), mask));
}

// ---------- prep: x->f16 (plain cached stores: coalesced 8B/lane merges in L2),
// W->bf16 transposed, degree histogram (NT on the read-once tgt stream) ----------
__global__ __launch_bounds__(256) void k_prep(const float* __restrict__ x,
                                              unsigned* __restrict__ xh, int nf4,
                                              const float* __restrict__ W1,
                                              const float* __restrict__ W2,
                                              unsigned short* __restrict__ W1t,
                                              unsigned short* __restrict__ W2t,
                                              const int* __restrict__ tgt,
                                              int* __restrict__ deg, int E) {
    int i0 = blockIdx.x * blockDim.x + threadIdx.x;
    int stride = gridDim.x * blockDim.x;
    const float4v* x4 = reinterpret_cast<const float4v*>(x);
    uint2v* xh2 = reinterpret_cast<uint2v*>(xh);
    for (int i = i0; i < nf4; i += stride) {
        float4v v = x4[i];
        uint2v o;
        o.x = pack_f16(v.x, v.y);
        o.y = pack_f16(v.z, v.w);
        xh2[i] = o;
    }
    if (i0 < 16384) {
        int k = i0 >> 7, nn = i0 & 127;
        W1t[nn * 128 + k] = us_bf16(W1[i0]);
        W2t[nn * 128 + k] = us_bf16(W2[i0]);
    }
    int E4 = E >> 2;
    const int4v* tgt4 = reinterpret_cast<const int4v*>(tgt);
    for (int q = i0; q < E4; q += stride) {
        int4v t4 = __builtin_nontemporal_load(&tgt4[q]);
        atomicAdd(&deg[t4.x], 1);
        atomicAdd(&deg[t4.y], 1);
        atomicAdd(&deg[t4.z], 1);
        atomicAdd(&deg[t4.w], 1);
    }
    for (int e = E4 * 4 + i0; e < E; e += stride)
        atomicAdd(&deg[tgt[e]], 1);
}

// ---------- CSR scan ----------
__global__ __launch_bounds__(SCAN_T) void k_scan_local(const int* __restrict__ deg,
                                                       int* __restrict__ rowptr,
                                                       int* __restrict__ part, int n) {
    __shared__ int sh[SCAN_T];
    int base = blockIdx.x * SCAN_CHUNK + threadIdx.x * SCAN_I;
    int v[SCAN_I]; int tsum = 0;
    #pragma unroll
    for (int k = 0; k < SCAN_I; ++k) { int idx = base + k; v[k] = (idx < n) ? deg[idx] : 0; tsum += v[k]; }
    sh[threadIdx.x] = tsum; __syncthreads();
    for (int off = 1; off < SCAN_T; off <<= 1) {
        int o = (threadIdx.x >= (unsigned)off) ? sh[threadIdx.x - off] : 0;
        __syncthreads();
        sh[threadIdx.x] += o;
        __syncthreads();
    }
    int excl = sh[threadIdx.x] - tsum;
    #pragma unroll
    for (int k = 0; k < SCAN_I; ++k) { int idx = base + k; if (idx < n) rowptr[idx] = excl; excl += v[k]; }
    if (threadIdx.x == 0) part[blockIdx.x] = sh[SCAN_T - 1];
}

// finalizes rowptr and seeds per-bucket append cursors (bcur[b] = rowptr[b<<BSH])
__global__ __launch_bounds__(256) void k_scan_add(int* __restrict__ rowptr,
                                                  int* __restrict__ bcur,
                                                  const int* __restrict__ part,
                                                  int nblk, int n, int E) {
    __shared__ int sp[256];
    int t = threadIdx.x;
    int v = (t < nblk) ? part[t] : 0;
    sp[t] = v; __syncthreads();
    for (int off = 1; off < 256; off <<= 1) {
        int o = (t >= off) ? sp[t - off] : 0;
        __syncthreads();
        sp[t] += o;
        __syncthreads();
    }
    int i = blockIdx.x * blockDim.x + t;
    if (i <= n) {
        int c = i / SCAN_CHUNK;
        int add = (c == 0) ? 0 : sp[c - 1];
        if (i < n) {
            int r = rowptr[i] + add;
            rowptr[i] = r;
            if ((i & ((1 << BSH) - 1)) == 0) bcur[i >> BSH] = r;
        } else rowptr[n] = E;
    }
}

// ---------- pass A: LDS-binned bucket append ----------
__global__ __launch_bounds__(256) void k_binA(
    const int* __restrict__ src, const int* __restrict__ tgt,
    const float* __restrict__ ew, int* __restrict__ bcur,
    int2* __restrict__ stage, int E, int nbuk)
{
    __shared__ int2 recs[CH];
    __shared__ unsigned short bslot[CH];
    __shared__ int sh[256];
    __shared__ int lbase[256];
    __shared__ int gofs[256];

    int tid = threadIdx.x;
    int c0 = blockIdx.x * CH;
    int chunkCnt = min(CH, E - c0);

    sh[tid] = 0;
    __syncthreads();

    int myb[8], mypos[8], mysrc[8]; unsigned myy[8];
    #pragma unroll
    for (int k = 0; k < 8; ++k) {
        int idx = k * 256 + tid;
        myb[k] = -1;
        if (idx < chunkCnt) {
            int e = c0 + idx;
            int t = tgt[e];
            int b = t >> BSH;
            float expw = __expf(ew[e]);
            unsigned short h = __builtin_bit_cast(unsigned short, (_Float16)expw);
            myb[k] = b;
            myy[k] = ((unsigned)(t & ((1 << BSH) - 1)) << 16) | (unsigned)h;
            mysrc[k] = src[e];
            mypos[k] = atomicAdd(&sh[b], 1);
        }
    }
    __syncthreads();
    int cnt_b = sh[tid];
    for (int off = 1; off < 256; off <<= 1) {
        int o = (tid >= off) ? sh[tid - off] : 0;
        __syncthreads();
        sh[tid] += o;
        __syncthreads();
    }
    int lb = sh[tid] - cnt_b;
    lbase[tid] = lb;
    if (cnt_b > 0 && tid < nbuk) {
        int gb = atomicAdd(&bcur[tid], cnt_b);
        gofs[tid] = gb - lb;
    }
    __syncthreads();
    #pragma unroll
    for (int k = 0; k < 8; ++k) {
        if (myb[k] >= 0) {
            int slot = lbase[myb[k]] + mypos[k];
            recs[slot] = make_int2(mysrc[k], (int)myy[k]);
            bslot[slot] = (unsigned short)myb[k];
        }
    }
    __syncthreads();
    for (int i = tid; i < chunkCnt; i += 256) {
        int b = bslot[i];
        stage[gofs[b] + i] = recs[i];
    }
}

// ---------- pass B: per-bucket scatter to final CSR + softmax normalize ----------
__global__ __launch_bounds__(256) void k_binB(
    const int* __restrict__ rowptr, const int2* __restrict__ stage,
    int2* __restrict__ csr, int n)
{
    __shared__ int lcur[1 << BSH];
    __shared__ float ldenom[1 << BSH];
    int b = blockIdx.x;
    int tid = threadIdx.x;
    int node0 = b << BSH;
    int nn = min(1 << BSH, n - node0);
    for (int j = tid; j < nn; j += 256) {
        lcur[j] = rowptr[node0 + j];
        ldenom[j] = 0.f;
    }
    __syncthreads();
    int s0 = rowptr[node0];
    int s1 = rowptr[min(node0 + (1 << BSH), n)];
    for (int i = s0 + tid; i < s1; i += 256) {
        int2 rec = stage[i];
        int tl = ((unsigned)rec.y) >> 16;
        _Float16 hw = __builtin_bit_cast(_Float16, (unsigned short)(rec.y & 0xffff));
        atomicAdd(&ldenom[tl], (float)hw);
    }
    __syncthreads();
    for (int j = tid; j < nn; j += 256) {
        float d = ldenom[j];
        ldenom[j] = (d > 0.f) ? (1.f / d) : 0.f;
    }
    __syncthreads();
    for (int i = s0 + tid; i < s1; i += 256) {
        int2 rec = stage[i];
        int tl = ((unsigned)rec.y) >> 16;
        _Float16 hw = __builtin_bit_cast(_Float16, (unsigned short)(rec.y & 0xffff));
        float wn = (float)hw * ldenom[tl];
        unsigned short wb = __builtin_bit_cast(unsigned short, (_Float16)wn);
        unsigned wp = (unsigned)wb | ((unsigned)wb << 16);
        int pos = atomicAdd(&lcur[tl], 1);
        csr[pos] = make_int2(rec.x, (int)wp);
    }
}

// ---------- aggregate: 1 wave per node; pure gather (weights pre-normalized) ----------
__global__ __launch_bounds__(256) void k_agg(
    const int* __restrict__ rowptr, const int2* __restrict__ csr,
    const uint4v* __restrict__ xh4, uint4v* __restrict__ cmb4, int n)
{
    int w = threadIdx.x >> 6;
    int lane = threadIdx.x & 63;
    int node = blockIdx.x * 4 + w;
    if (node >= n) node = n - 1;   // benign duplicate on tail

    int r0 = rowptr[node], r1 = rowptr[node + 1];
    int cnt = r1 - r0;

    int eg = lane >> 4;
    int dg = lane & 15;

    half2_t h0 = (half2_t)0, h1 = (half2_t)0, h2 = (half2_t)0, h3 = (half2_t)0;

    int last = (cnt > 0) ? cnt - 1 : 0;
    for (int base = 0; base < cnt; base += 16) {
        #pragma unroll
        for (int i = 0; i < 4; ++i) {
            if (base + i * 4 >= cnt) break;    // wave-uniform
            int e = base + i * 4 + eg;
            bool valid = e < cnt;
            int2 cr = csr[r0 + (valid ? e : last)];
            half2_t w2 = as_h2(valid ? (unsigned)cr.y : 0u);
            uint4v v = xh4[cr.x * 16 + dg];
            h0 += w2 * as_h2(v.x);
            h1 += w2 * as_h2(v.y);
            h2 += w2 * as_h2(v.z);
            h3 += w2 * as_h2(v.w);
        }
    }

    h0 += shfl_h2(h0, 16); h0 += shfl_h2(h0, 32);
    h1 += shfl_h2(h1, 16); h1 += shfl_h2(h1, 32);
    h2 += shfl_h2(h2, 16); h2 += shfl_h2(h2, 32);
    h3 += shfl_h2(h3, 16); h3 += shfl_h2(h3, 32);

    float a0 = (float)h0.x, a1 = (float)h0.y, a2 = (float)h1.x, a3 = (float)h1.y;
    float a4 = (float)h2.x, a5 = (float)h2.y, a6 = (float)h3.x, a7 = (float)h3.y;

    float ss = a0 * a0;
    ss = fmaf(a1, a1, ss); ss = fmaf(a2, a2, ss); ss = fmaf(a3, a3, ss);
    ss = fmaf(a4, a4, ss); ss = fmaf(a5, a5, ss); ss = fmaf(a6, a6, ss);
    ss = fmaf(a7, a7, ss);
    #pragma unroll
    for (int off = 8; off; off >>= 1) ss += __shfl_xor(ss, off);
    float rn = 1.f / (sqrtf(ss) + 1e-9f);

    if (eg == 0) {
        uint4v hx = xh4[node * 16 + dg];
        half2_t x0 = as_h2(hx.x), x1 = as_h2(hx.y), x2 = as_h2(hx.z), x3 = as_h2(hx.w);
        uint4v o;
        o.x = pack_bf16((float)x0.x + a0 * rn, (float)x0.y + a1 * rn);
        o.y = pack_bf16((float)x1.x + a2 * rn, (float)x1.y + a3 * rn);
        o.z = pack_bf16((float)x2.x + a4 * rn, (float)x2.y + a5 * rn);
        o.w = pack_bf16((float)x3.x + a6 * rn, (float)x3.y + a7 * rn);
        cmb4[node * 16 + dg] = o;
    }
}

// ---------- MLP + LN via MFMA: 64 nodes/block; W read from global (L1/L2) ----------
__global__ __launch_bounds__(256) void k_mlp(
    const uint4v* __restrict__ cmb4,
    const unsigned short* __restrict__ W1t, const unsigned short* __restrict__ W2t,
    const float* __restrict__ b1, const float* __restrict__ b2,
    const float* __restrict__ gamma, const float* __restrict__ beta,
    float* __restrict__ out, int n)
{
    __shared__ __align__(16) unsigned short sA[64][136];

    int node0 = blockIdx.x * 64;
    int w = threadIdx.x >> 6;
    int lane = threadIdx.x & 63;
    int lr = lane & 15;
    int lg = lane >> 4;
    int mr = w * 16;

    for (int idx = threadIdx.x; idx < 64 * 16; idx += 256) {
        int row = idx >> 4, seg = idx & 15;
        int gr = node0 + row; if (gr >= n) gr = n - 1;
        uint4v v = cmb4[gr * 16 + seg];
        *reinterpret_cast<uint4v*>(&sA[row][seg * 8]) = v;
    }
    __syncthreads();

    short8 aF[4];
    #pragma unroll
    for (int kt = 0; kt < 4; ++kt)
        aF[kt] = *reinterpret_cast<const short8*>(&sA[mr + lr][kt * 32 + lg * 8]);

    #pragma unroll
    for (int nt = 0; nt < 8; ++nt) {
        f32x4 c = {0.f, 0.f, 0.f, 0.f};
        #pragma unroll
        for (int kt = 0; kt < 4; ++kt) {
            short8 bF = *reinterpret_cast<const short8*>(
                &W1t[(nt * 16 + lr) * 128 + kt * 32 + lg * 8]);
            c = __builtin_amdgcn_mfma_f32_16x16x32_bf16(aF[kt], bF, c, 0, 0, 0);
        }
        float b1v = b1[nt * 16 + lr];
        #pragma unroll
        for (int reg = 0; reg < 4; ++reg) {
            float h = fmaxf(c[reg] + b1v, 0.f);
            sA[mr + lg * 4 + reg][nt * 16 + lr] = us_bf16(h);
        }
    }
    __syncthreads();

    short8 a2F[4];
    #pragma unroll
    for (int kt = 0; kt < 4; ++kt)
        a2F[kt] = *reinterpret_cast<const short8*>(&sA[mr + lr][kt * 32 + lg * 8]);

    f32x4 c2[8];
    float b2v[8], gv[8], bev[8];
    #pragma unroll
    for (int nt = 0; nt < 8; ++nt) {
        c2[nt] = (f32x4){0.f, 0.f, 0.f, 0.f};
        #pragma unroll
        for (int kt = 0; kt < 4; ++kt) {
            short8 bF = *reinterpret_cast<const short8*>(
                &W2t[(nt * 16 + lr) * 128 + kt * 32 + lg * 8]);
            c2[nt] = __builtin_amdgcn_mfma_f32_16x16x32_bf16(a2F[kt], bF, c2[nt], 0, 0, 0);
        }
        int col = nt * 16 + lr;
        b2v[nt] = b2[col]; gv[nt] = gamma[col]; bev[nt] = beta[col];
    }

    float rs[4] = {0.f, 0.f, 0.f, 0.f}, sq[4] = {0.f, 0.f, 0.f, 0.f};
    #pragma unroll
    for (int nt = 0; nt < 8; ++nt)
        #pragma unroll
        for (int reg = 0; reg < 4; ++reg) {
            float v = c2[nt][reg] + b2v[nt];
            rs[reg] += v; sq[reg] += v * v;
        }
    #pragma unroll
    for (int off = 1; off <= 8; off <<= 1)
        #pragma unroll
        for (int reg = 0; reg < 4; ++reg) {
            rs[reg] += __shfl_xor(rs[reg], off);
            sq[reg] += __shfl_xor(sq[reg], off);
        }
    float mu[4], rstd[4];
    #pragma unroll
    for (int reg = 0; reg < 4; ++reg) {
        mu[reg] = rs[reg] * (1.f / 128.f);
        float var = sq[reg] * (1.f / 128.f) - mu[reg] * mu[reg];
        rstd[reg] = rsqrtf(var + 1e-5f);
    }

    #pragma unroll
    for (int nt = 0; nt < 8; ++nt)
        #pragma unroll
        for (int reg = 0; reg < 4; ++reg) {
            int gr = node0 + mr + lg * 4 + reg;
            if (gr < n) {
                float v = c2[nt][reg] + b2v[nt];
                out[gr * 128 + nt * 16 + lr] = gv[nt] * (v - mu[reg]) * rstd[reg] + bev[nt];
            }
        }
}

extern "C" void kernel_launch(void* const* d_in, const int* in_sizes, int n_in,
                              void* d_out, int out_size, void* d_ws, size_t ws_size,
                              hipStream_t stream) {
    const float* x     = (const float*)d_in[0];
    const int*   ei    = (const int*)d_in[1];
    const float* ew    = (const float*)d_in[2];
    const float* W1    = (const float*)d_in[3];
    const float* b1    = (const float*)d_in[4];
    const float* W2    = (const float*)d_in[5];
    const float* b2    = (const float*)d_in[6];
    const float* gamma = (const float*)d_in[7];
    const float* beta  = (const float*)d_in[8];

    int n = in_sizes[0] / D;
    int E = in_sizes[2];
    const int* src = ei;
    const int* tgt = ei + E;

    char* ws = (char*)d_ws;
    int2*     csr    = (int2*)ws;     ws += (size_t)E * sizeof(int2);
    unsigned* xh     = (unsigned*)ws; ws += (size_t)n * 64 * sizeof(unsigned);
    unsigned* cmb    = (unsigned*)ws; ws += (size_t)n * 64 * sizeof(unsigned);
    unsigned short* W1t = (unsigned short*)ws; ws += 128 * 128 * sizeof(unsigned short);
    unsigned short* W2t = (unsigned short*)ws; ws += 128 * 128 * sizeof(unsigned short);
    int*      deg    = (int*)ws;      ws += (size_t)n * sizeof(int);
    int*      rowptr = (int*)ws;      ws += ((size_t)n + 1) * sizeof(int);
    int*      bcur   = (int*)ws;      ws += 256 * sizeof(int);
    int*      part   = (int*)ws;      ws += (size_t)SCAN_T * sizeof(int);
    // stage aliases cmb: stage is consumed by k_binB before k_agg writes cmb
    int2*     stage  = (int2*)cmb;

    hipMemsetAsync((void*)deg, 0, (size_t)n * sizeof(int), stream);

    int nf4 = n * D / 4;
    k_prep<<<2048, 256, 0, stream>>>(x, xh, nf4, W1, W2, W1t, W2t, tgt, deg, E);

    int nblk = (n + SCAN_CHUNK - 1) / SCAN_CHUNK;   // 98 (<=256)
    k_scan_local<<<nblk, SCAN_T, 0, stream>>>(deg, rowptr, part, n);
    k_scan_add<<<(n + 256) / 256, 256, 0, stream>>>(rowptr, bcur, part, nblk, n, E);

    int nbuk = (n + (1 << BSH) - 1) >> BSH;         // 196 for n=100000
    int nchunk = (E + CH - 1) / CH;                 // 782
    k_binA<<<nchunk, 256, 0, stream>>>(src, tgt, ew, bcur, stage, E, nbuk);
    k_binB<<<nbuk, 256, 0, stream>>>(rowptr, stage, csr, n);

    k_agg<<<(n + 3) / 4, 256, 0, stream>>>(rowptr, csr,
                                           (const uint4v*)xh, (uint4v*)cmb, n);

    k_mlp<<<(n + 63) / 64, 256, 0, stream>>>((const uint4v*)cmb, W1t, W2t,
                                             b1, b2, gamma, beta,
                                             (float*)d_out, n);
}

// Round 11
// 253.724 us; speedup vs baseline: 1.2805x; 1.1020x over previous
//
#include <hip/hip_runtime.h>
#include <hip/hip_bf16.h>

#define D 128
#define CH 2048          // edges per k_binA block
#define BSH 9            // log2(nodes per bucket) -> 512; valid for n <= 131072
#define CNT_BLK 512      // blocks doing bucket counting in k_prep

typedef __attribute__((ext_vector_type(8))) short short8;
typedef __attribute__((ext_vector_type(4))) float f32x4;
typedef __attribute__((ext_vector_type(4))) int int4v;
typedef __attribute__((ext_vector_type(2))) int int2v;
typedef __attribute__((ext_vector_type(4))) float float4v;
typedef __attribute__((ext_vector_type(4))) unsigned uint4v;
typedef __attribute__((ext_vector_type(2))) unsigned uint2v;
typedef _Float16 half2_t __attribute__((ext_vector_type(2)));

__device__ __forceinline__ unsigned short us_bf16(float f) {
    return __bfloat16_as_ushort(__float2bfloat16(f));
}
__device__ __forceinline__ unsigned pack_bf16(float a, float b) {
    return (unsigned)us_bf16(a) | ((unsigned)us_bf16(b) << 16);
}
__device__ __forceinline__ unsigned pack_f16(float a, float b) {
    unsigned short ua = __builtin_bit_cast(unsigned short, (_Float16)a);
    unsigned short ub = __builtin_bit_cast(unsigned short, (_Float16)b);
    return (unsigned)ua | ((unsigned)ub << 16);
}
__device__ __forceinline__ half2_t as_h2(unsigned u) {
    return __builtin_bit_cast(half2_t, u);
}
__device__ __forceinline__ half2_t shfl_h2(half2_t v, int mask) {
    return __builtin_bit_cast(half2_t,
        (unsigned)__shfl_xor(__builtin_bit_cast(int, v), mask));
}
__device__ __forceinline__ int2v nt_load2(const int2* p) {
    return __builtin_nontemporal_load(reinterpret_cast<const int2v*>(p));
}

// ---------- prep: x->f16, W->bf16 transposed, per-BUCKET count (196 bins in LDS).
// No per-node histogram: 1.6M scattered global atomics are gone.
__global__ __launch_bounds__(256) void k_prep(const float* __restrict__ x,
                                              unsigned* __restrict__ xh, int nf4,
                                              const float* __restrict__ W1,
                                              const float* __restrict__ W2,
                                              unsigned short* __restrict__ W1t,
                                              unsigned short* __restrict__ W2t,
                                              const int* __restrict__ tgt,
                                              int* __restrict__ bcnt, int E, int nbuk) {
    int tid = threadIdx.x;
    int i0 = blockIdx.x * blockDim.x + tid;
    int stride = gridDim.x * blockDim.x;
    const float4v* x4 = reinterpret_cast<const float4v*>(x);
    uint2v* xh2 = reinterpret_cast<uint2v*>(xh);
    for (int i = i0; i < nf4; i += stride) {
        float4v v = x4[i];
        uint2v o;
        o.x = pack_f16(v.x, v.y);
        o.y = pack_f16(v.z, v.w);
        xh2[i] = o;
    }
    if (i0 < 16384) {
        int k = i0 >> 7, nn = i0 & 127;
        W1t[nn * 128 + k] = us_bf16(W1[i0]);
        W2t[nn * 128 + k] = us_bf16(W2[i0]);
    }
    // bucket counting on a subset of blocks
    __shared__ int hist[256];
    if (blockIdx.x < CNT_BLK) {
        hist[tid] = 0;
        __syncthreads();
        int c0 = blockIdx.x * 256 + tid;
        int cstride = CNT_BLK * 256;
        int E4 = E >> 2;
        const int4v* tgt4 = reinterpret_cast<const int4v*>(tgt);
        for (int q = c0; q < E4; q += cstride) {
            int4v t4 = __builtin_nontemporal_load(&tgt4[q]);
            atomicAdd(&hist[t4.x >> BSH], 1);
            atomicAdd(&hist[t4.y >> BSH], 1);
            atomicAdd(&hist[t4.z >> BSH], 1);
            atomicAdd(&hist[t4.w >> BSH], 1);
        }
        for (int e = E4 * 4 + c0; e < E; e += cstride)
            atomicAdd(&hist[tgt[e] >> BSH], 1);
        __syncthreads();
        if (tid < nbuk && hist[tid] > 0) atomicAdd(&bcnt[tid], hist[tid]);
    }
}

// ---------- tiny: scan bucket counts -> bbase/bcur; set rowptr[n]=E ----------
__global__ __launch_bounds__(256) void k_scanB(const int* __restrict__ bcnt,
                                               int* __restrict__ bbase,
                                               int* __restrict__ bcur,
                                               int* __restrict__ rowptr,
                                               int nbuk, int n, int E) {
    __shared__ int sp[256];
    int t = threadIdx.x;
    int v = (t < nbuk) ? bcnt[t] : 0;
    sp[t] = v; __syncthreads();
    for (int off = 1; off < 256; off <<= 1) {
        int o = (t >= off) ? sp[t - off] : 0;
        __syncthreads();
        sp[t] += o;
        __syncthreads();
    }
    int excl = sp[t] - v;
    if (t < nbuk) { bbase[t] = excl; bcur[t] = excl; }
    if (t == 0) { bbase[nbuk] = E; rowptr[n] = E; }
}

// ---------- pass A: LDS-binned bucket append ----------
__global__ __launch_bounds__(256) void k_binA(
    const int* __restrict__ src, const int* __restrict__ tgt,
    const float* __restrict__ ew, int* __restrict__ bcur,
    int2* __restrict__ stage, int E, int nbuk)
{
    __shared__ int2 recs[CH];
    __shared__ unsigned short bslot[CH];
    __shared__ int sh[256];
    __shared__ int lbase[256];
    __shared__ int gofs[256];

    int tid = threadIdx.x;
    int c0 = blockIdx.x * CH;
    int chunkCnt = min(CH, E - c0);

    sh[tid] = 0;
    __syncthreads();

    int myb[8], mypos[8], mysrc[8]; unsigned myy[8];
    #pragma unroll
    for (int k = 0; k < 8; ++k) {
        int idx = k * 256 + tid;
        myb[k] = -1;
        if (idx < chunkCnt) {
            int e = c0 + idx;
            int t = __builtin_nontemporal_load(&tgt[e]);
            int b = t >> BSH;
            float expw = __expf(__builtin_nontemporal_load(&ew[e]));
            unsigned short h = __builtin_bit_cast(unsigned short, (_Float16)expw);
            myb[k] = b;
            myy[k] = ((unsigned)(t & ((1 << BSH) - 1)) << 16) | (unsigned)h;
            mysrc[k] = __builtin_nontemporal_load(&src[e]);
            mypos[k] = atomicAdd(&sh[b], 1);
        }
    }
    __syncthreads();
    int cnt_b = sh[tid];
    for (int off = 1; off < 256; off <<= 1) {
        int o = (tid >= off) ? sh[tid - off] : 0;
        __syncthreads();
        sh[tid] += o;
        __syncthreads();
    }
    int lb = sh[tid] - cnt_b;
    lbase[tid] = lb;
    if (cnt_b > 0 && tid < nbuk) {
        int gb = atomicAdd(&bcur[tid], cnt_b);
        gofs[tid] = gb - lb;
    }
    __syncthreads();
    #pragma unroll
    for (int k = 0; k < 8; ++k) {
        if (myb[k] >= 0) {
            int slot = lbase[myb[k]] + mypos[k];
            recs[slot] = make_int2(mysrc[k], (int)myy[k]);
            bslot[slot] = (unsigned short)myb[k];
        }
    }
    __syncthreads();
    for (int i = tid; i < chunkCnt; i += 256) {
        int b = bslot[i];
        stage[gofs[b] + i] = recs[i];
    }
}

// ---------- pass B: per-bucket CSR build (count+scan+rowptr in LDS) + normalize ----------
__global__ __launch_bounds__(256) void k_binB(
    const int* __restrict__ bbase, const int2* __restrict__ stage,
    int2* __restrict__ csr, int* __restrict__ rowptr, int n)
{
    __shared__ int lcnt[1 << BSH];     // counts, then cursors
    __shared__ float ldenom[1 << BSH];
    __shared__ int sc[256];
    int b = blockIdx.x;
    int tid = threadIdx.x;
    int node0 = b << BSH;
    int nn = min(1 << BSH, n - node0);
    int s0 = bbase[b], s1 = bbase[b + 1];

    for (int j = tid; j < (1 << BSH); j += 256) { lcnt[j] = 0; ldenom[j] = 0.f; }
    __syncthreads();

    // pass 1: per-node count + softmax denominator
    for (int i = s0 + tid; i < s1; i += 256) {
        int2v rec = nt_load2(&stage[i]);
        int tl = ((unsigned)rec.y) >> 16;
        _Float16 hw = __builtin_bit_cast(_Float16, (unsigned short)(rec.y & 0xffff));
        atomicAdd(&lcnt[tl], 1);
        atomicAdd(&ldenom[tl], (float)hw);
    }
    __syncthreads();

    // invert denominators
    for (int j = tid; j < (1 << BSH); j += 256) {
        float d = ldenom[j];
        ldenom[j] = (d > 0.f) ? (1.f / d) : 0.f;
    }
    // scan 512 counts with 256 threads (2 per thread) -> rowptr + cursors
    int v0 = lcnt[2 * tid], v1 = lcnt[2 * tid + 1];
    int tsum = v0 + v1;
    sc[tid] = tsum;
    __syncthreads();
    for (int off = 1; off < 256; off <<= 1) {
        int o = (tid >= off) ? sc[tid - off] : 0;
        __syncthreads();
        sc[tid] += o;
        __syncthreads();
    }
    int excl = sc[tid] - tsum;
    int p0 = s0 + excl, p1 = s0 + excl + v0;
    if (2 * tid < nn)     rowptr[node0 + 2 * tid] = p0;
    if (2 * tid + 1 < nn) rowptr[node0 + 2 * tid + 1] = p1;
    __syncthreads();
    lcnt[2 * tid] = p0;
    lcnt[2 * tid + 1] = p1;
    __syncthreads();

    // pass 2: scatter normalized records into block-private csr window
    for (int i = s0 + tid; i < s1; i += 256) {
        int2v rec = nt_load2(&stage[i]);
        int tl = ((unsigned)rec.y) >> 16;
        _Float16 hw = __builtin_bit_cast(_Float16, (unsigned short)(rec.y & 0xffff));
        float wn = (float)hw * ldenom[tl];
        unsigned short wb = __builtin_bit_cast(unsigned short, (_Float16)wn);
        unsigned wp = (unsigned)wb | ((unsigned)wb << 16);
        int pos = atomicAdd(&lcnt[tl], 1);
        csr[pos] = make_int2(rec.x, (int)wp);
    }
}

// ---------- aggregate: 1 wave per node; pure gather (weights pre-normalized) ----------
__global__ __launch_bounds__(256) void k_agg(
    const int* __restrict__ rowptr, const int2* __restrict__ csr,
    const uint4v* __restrict__ xh4, uint4v* __restrict__ cmb4, int n)
{
    int w = threadIdx.x >> 6;
    int lane = threadIdx.x & 63;
    int node = blockIdx.x * 4 + w;
    if (node >= n) node = n - 1;   // benign duplicate on tail

    int r0 = rowptr[node], r1 = rowptr[node + 1];
    int cnt = r1 - r0;

    int eg = lane >> 4;
    int dg = lane & 15;

    half2_t h0 = (half2_t)0, h1 = (half2_t)0, h2 = (half2_t)0, h3 = (half2_t)0;

    int last = (cnt > 0) ? cnt - 1 : 0;
    for (int base = 0; base < cnt; base += 16) {
        #pragma unroll
        for (int i = 0; i < 4; ++i) {
            if (base + i * 4 >= cnt) break;    // wave-uniform
            int e = base + i * 4 + eg;
            bool valid = e < cnt;
            int2v cr = nt_load2(&csr[r0 + (valid ? e : last)]);
            half2_t w2 = as_h2(valid ? (unsigned)cr.y : 0u);
            uint4v v = xh4[cr.x * 16 + dg];
            h0 += w2 * as_h2(v.x);
            h1 += w2 * as_h2(v.y);
            h2 += w2 * as_h2(v.z);
            h3 += w2 * as_h2(v.w);
        }
    }

    h0 += shfl_h2(h0, 16); h0 += shfl_h2(h0, 32);
    h1 += shfl_h2(h1, 16); h1 += shfl_h2(h1, 32);
    h2 += shfl_h2(h2, 16); h2 += shfl_h2(h2, 32);
    h3 += shfl_h2(h3, 16); h3 += shfl_h2(h3, 32);

    float a0 = (float)h0.x, a1 = (float)h0.y, a2 = (float)h1.x, a3 = (float)h1.y;
    float a4 = (float)h2.x, a5 = (float)h2.y, a6 = (float)h3.x, a7 = (float)h3.y;

    float ss = a0 * a0;
    ss = fmaf(a1, a1, ss); ss = fmaf(a2, a2, ss); ss = fmaf(a3, a3, ss);
    ss = fmaf(a4, a4, ss); ss = fmaf(a5, a5, ss); ss = fmaf(a6, a6, ss);
    ss = fmaf(a7, a7, ss);
    #pragma unroll
    for (int off = 8; off; off >>= 1) ss += __shfl_xor(ss, off);
    float rn = 1.f / (sqrtf(ss) + 1e-9f);

    if (eg == 0) {
        uint4v hx = xh4[node * 16 + dg];
        half2_t x0 = as_h2(hx.x), x1 = as_h2(hx.y), x2 = as_h2(hx.z), x3 = as_h2(hx.w);
        uint4v o;
        o.x = pack_bf16((float)x0.x + a0 * rn, (float)x0.y + a1 * rn);
        o.y = pack_bf16((float)x1.x + a2 * rn, (float)x1.y + a3 * rn);
        o.z = pack_bf16((float)x2.x + a4 * rn, (float)x2.y + a5 * rn);
        o.w = pack_bf16((float)x3.x + a6 * rn, (float)x3.y + a7 * rn);
        cmb4[node * 16 + dg] = o;
    }
}

// ---------- MLP + LN via MFMA: 64 nodes/block; W read from global (L1/L2) ----------
__global__ __launch_bounds__(256) void k_mlp(
    const uint4v* __restrict__ cmb4,
    const unsigned short* __restrict__ W1t, const unsigned short* __restrict__ W2t,
    const float* __restrict__ b1, const float* __restrict__ b2,
    const float* __restrict__ gamma, const float* __restrict__ beta,
    float* __restrict__ out, int n)
{
    __shared__ __align__(16) unsigned short sA[64][136];

    int node0 = blockIdx.x * 64;
    int w = threadIdx.x >> 6;
    int lane = threadIdx.x & 63;
    int lr = lane & 15;
    int lg = lane >> 4;
    int mr = w * 16;

    for (int idx = threadIdx.x; idx < 64 * 16; idx += 256) {
        int row = idx >> 4, seg = idx & 15;
        int gr = node0 + row; if (gr >= n) gr = n - 1;
        uint4v v = cmb4[gr * 16 + seg];
        *reinterpret_cast<uint4v*>(&sA[row][seg * 8]) = v;
    }
    __syncthreads();

    short8 aF[4];
    #pragma unroll
    for (int kt = 0; kt < 4; ++kt)
        aF[kt] = *reinterpret_cast<const short8*>(&sA[mr + lr][kt * 32 + lg * 8]);

    #pragma unroll
    for (int nt = 0; nt < 8; ++nt) {
        f32x4 c = {0.f, 0.f, 0.f, 0.f};
        #pragma unroll
        for (int kt = 0; kt < 4; ++kt) {
            short8 bF = *reinterpret_cast<const short8*>(
                &W1t[(nt * 16 + lr) * 128 + kt * 32 + lg * 8]);
            c = __builtin_amdgcn_mfma_f32_16x16x32_bf16(aF[kt], bF, c, 0, 0, 0);
        }
        float b1v = b1[nt * 16 + lr];
        #pragma unroll
        for (int reg = 0; reg < 4; ++reg) {
            float h = fmaxf(c[reg] + b1v, 0.f);
            sA[mr + lg * 4 + reg][nt * 16 + lr] = us_bf16(h);
        }
    }
    __syncthreads();

    short8 a2F[4];
    #pragma unroll
    for (int kt = 0; kt < 4; ++kt)
        a2F[kt] = *reinterpret_cast<const short8*>(&sA[mr + lr][kt * 32 + lg * 8]);

    f32x4 c2[8];
    float b2v[8], gv[8], bev[8];
    #pragma unroll
    for (int nt = 0; nt < 8; ++nt) {
        c2[nt] = (f32x4){0.f, 0.f, 0.f, 0.f};
        #pragma unroll
        for (int kt = 0; kt < 4; ++kt) {
            short8 bF = *reinterpret_cast<const short8*>(
                &W2t[(nt * 16 + lr) * 128 + kt * 32 + lg * 8]);
            c2[nt] = __builtin_amdgcn_mfma_f32_16x16x32_bf16(a2F[kt], bF, c2[nt], 0, 0, 0);
        }
        int col = nt * 16 + lr;
        b2v[nt] = b2[col]; gv[nt] = gamma[col]; bev[nt] = beta[col];
    }

    float rs[4] = {0.f, 0.f, 0.f, 0.f}, sq[4] = {0.f, 0.f, 0.f, 0.f};
    #pragma unroll
    for (int nt = 0; nt < 8; ++nt)
        #pragma unroll
        for (int reg = 0; reg < 4; ++reg) {
            float v = c2[nt][reg] + b2v[nt];
            rs[reg] += v; sq[reg] += v * v;
        }
    #pragma unroll
    for (int off = 1; off <= 8; off <<= 1)
        #pragma unroll
        for (int reg = 0; reg < 4; ++reg) {
            rs[reg] += __shfl_xor(rs[reg], off);
            sq[reg] += __shfl_xor(sq[reg], off);
        }
    float mu[4], rstd[4];
    #pragma unroll
    for (int reg = 0; reg < 4; ++reg) {
        mu[reg] = rs[reg] * (1.f / 128.f);
        float var = sq[reg] * (1.f / 128.f) - mu[reg] * mu[reg];
        rstd[reg] = rsqrtf(var + 1e-5f);
    }

    #pragma unroll
    for (int nt = 0; nt < 8; ++nt)
        #pragma unroll
        for (int reg = 0; reg < 4; ++reg) {
            int gr = node0 + mr + lg * 4 + reg;
            if (gr < n) {
                float v = c2[nt][reg] + b2v[nt];
                out[gr * 128 + nt * 16 + lr] = gv[nt] * (v - mu[reg]) * rstd[reg] + bev[nt];
            }
        }
}

extern "C" void kernel_launch(void* const* d_in, const int* in_sizes, int n_in,
                              void* d_out, int out_size, void* d_ws, size_t ws_size,
                              hipStream_t stream) {
    const float* x     = (const float*)d_in[0];
    const int*   ei    = (const int*)d_in[1];
    const float* ew    = (const float*)d_in[2];
    const float* W1    = (const float*)d_in[3];
    const float* b1    = (const float*)d_in[4];
    const float* W2    = (const float*)d_in[5];
    const float* b2    = (const float*)d_in[6];
    const float* gamma = (const float*)d_in[7];
    const float* beta  = (const float*)d_in[8];

    int n = in_sizes[0] / D;
    int E = in_sizes[2];
    const int* src = ei;
    const int* tgt = ei + E;

    char* ws = (char*)d_ws;
    int2*     csr    = (int2*)ws;     ws += (size_t)E * sizeof(int2);
    unsigned* xh     = (unsigned*)ws; ws += (size_t)n * 64 * sizeof(unsigned);
    unsigned* cmb    = (unsigned*)ws; ws += (size_t)n * 64 * sizeof(unsigned);
    unsigned short* W1t = (unsigned short*)ws; ws += 128 * 128 * sizeof(unsigned short);
    unsigned short* W2t = (unsigned short*)ws; ws += 128 * 128 * sizeof(unsigned short);
    int*      rowptr = (int*)ws;      ws += ((size_t)n + 1) * sizeof(int);
    int*      bcnt   = (int*)ws;      ws += 256 * sizeof(int);
    int*      bbase  = (int*)ws;      ws += 257 * sizeof(int);
    int*      bcur   = (int*)ws;      ws += 256 * sizeof(int);
    // stage aliases cmb: stage is consumed by k_binB before k_agg writes cmb
    int2*     stage  = (int2*)cmb;

    hipMemsetAsync((void*)bcnt, 0, 256 * sizeof(int), stream);

    int nbuk = (n + (1 << BSH) - 1) >> BSH;         // 196 for n=100000
    int nf4 = n * D / 4;
    k_prep<<<2048, 256, 0, stream>>>(x, xh, nf4, W1, W2, W1t, W2t, tgt, bcnt, E, nbuk);

    k_scanB<<<1, 256, 0, stream>>>(bcnt, bbase, bcur, rowptr, nbuk, n, E);

    int nchunk = (E + CH - 1) / CH;                 // 782
    k_binA<<<nchunk, 256, 0, stream>>>(src, tgt, ew, bcur, stage, E, nbuk);
    k_binB<<<nbuk, 256, 0, stream>>>(bbase, stage, csr, rowptr, n);

    k_agg<<<(n + 3) / 4, 256, 0, stream>>>(rowptr, csr,
                                           (const uint4v*)xh, (uint4v*)cmb, n);

    k_mlp<<<(n + 63) / 64, 256, 0, stream>>>((const uint4v*)cmb, W1t, W2t,
                                             b1, b2, gamma, beta,
                                             (float*)d_out, n);
}